// Round 1
// baseline (492.021 us; speedup 1.0000x reference)
//
#include <hip/hip_runtime.h>
#include <math.h>

// Problem constants (fixed by the reference):
constexpr int N = 262144;   // tokens
constexpr int B = 4096;     // segments
constexpr int D = 256;      // relation_embed_dim
constexpr int A = 128;      // attention_dim

constexpr int CHUNK  = 1024;       // queries elements per scan block
constexpr int NCHUNK = N / CHUNK;  // 256

// ---------- scan 1: per-chunk sums of queries ----------
__global__ void k_scan_partials(const int* __restrict__ q, int* __restrict__ partials) {
    int t = threadIdx.x;
    int4 v = ((const int4*)q)[blockIdx.x * (CHUNK / 4) + t];
    int s = v.x + v.y + v.z + v.w;
    __shared__ int sm[256];
    sm[t] = s; __syncthreads();
    for (int o = 128; o > 0; o >>= 1) {
        if (t < o) sm[t] += sm[t + o];
        __syncthreads();
    }
    if (t == 0) partials[blockIdx.x] = sm[0];
}

// ---------- scan 2: exclusive scan of 256 chunk sums ----------
__global__ void k_scan_offsets(const int* __restrict__ partials, int* __restrict__ offs) {
    int t = threadIdx.x;
    __shared__ int sm[256];
    int v = partials[t];
    sm[t] = v; __syncthreads();
    for (int o = 1; o < 256; o <<= 1) {
        int add = (t >= o) ? sm[t - o] : 0;
        __syncthreads();
        sm[t] += add;
        __syncthreads();
    }
    offs[t] = sm[t] - v;  // exclusive
}

// ---------- scan 3: per-token segment id + segment end indices ----------
__global__ void k_seg_ends(const int* __restrict__ q, const int* __restrict__ offs,
                           int* __restrict__ seg, int* __restrict__ ends) {
    int t = threadIdx.x;
    int4 v = ((const int4*)q)[blockIdx.x * (CHUNK / 4) + t];
    int tsum = v.x + v.y + v.z + v.w;
    __shared__ int sm[256];
    sm[t] = tsum; __syncthreads();
    for (int o = 1; o < 256; o <<= 1) {
        int add = (t >= o) ? sm[t - o] : 0;
        __syncthreads();
        sm[t] += add;
        __syncthreads();
    }
    int run = offs[blockIdx.x] + sm[t] - tsum;  // ones strictly before my first elem
    int base_idx = blockIdx.x * CHUNK + t * 4;
    int qq[4] = {v.x, v.y, v.z, v.w};
#pragma unroll
    for (int k = 0; k < 4; k++) {
        int idx = base_idx + k;
        seg[idx] = run;
        if (qq[k]) { ends[run] = idx; run++; }
    }
}

// ---------- M = Wk^T Wq  (D x D) ----------
__global__ void k_compute_M(const float* __restrict__ Wq, const float* __restrict__ Wk,
                            float* __restrict__ M) {
    int d2 = threadIdx.x;   // 0..255
    int d1 = blockIdx.x;    // 0..255
    float acc = 0.f;
#pragma unroll 4
    for (int a = 0; a < A; a++) {
        acc += Wk[a * D + d1] * Wq[a * D + d2];
    }
    M[d1 * D + d2] = acc;
}

// ---------- V[b] = M * x_{end_b}  (B x D) ----------
__global__ void k_compute_V(const float* __restrict__ X, const int* __restrict__ ends,
                            const float* __restrict__ M, float* __restrict__ V) {
    int b = blockIdx.x;
    int t = threadIdx.x;  // 256
    __shared__ float xs[D];
    int e = ends[b];
    xs[t] = X[(size_t)e * D + t];
    __syncthreads();
    const float4* Mrow = (const float4*)(M + t * D);
    const float4* xv = (const float4*)xs;
    float acc = 0.f;
#pragma unroll 8
    for (int j = 0; j < D / 4; j++) {
        float4 m4 = Mrow[j];
        float4 x4 = xv[j];
        acc += m4.x * x4.x + m4.y * x4.y + m4.z * x4.z + m4.w * x4.w;
    }
    V[b * D + t] = acc;
}

// ---------- logits[i] = x_i . V[seg[i]] : one wave (64 lanes x float4) per token ----------
__global__ void k_logits(const float* __restrict__ X, const int* __restrict__ seg,
                         const float* __restrict__ V, float* __restrict__ logits) {
    int wave = threadIdx.x >> 6;  // 0..3
    int lane = threadIdx.x & 63;
    int tok = blockIdx.x * 4 + wave;
    float4 x4 = ((const float4*)(X + (size_t)tok * D))[lane];
    int s = seg[tok];
    float4 v4 = ((const float4*)(V + (size_t)s * D))[lane];
    float p = x4.x * v4.x + x4.y * v4.y + x4.z * v4.z + x4.w * v4.w;
#pragma unroll
    for (int o = 32; o > 0; o >>= 1) p += __shfl_xor(p, o, 64);
    if (lane == 0) logits[tok] = p;
}

// ---------- per-segment softmax: one wave per segment ----------
__global__ void k_softmax(const float* __restrict__ logits, const int* __restrict__ ends,
                          float* __restrict__ out) {
    int wave = threadIdx.x >> 6;
    int lane = threadIdx.x & 63;
    int b = blockIdx.x * 4 + wave;
    int start = (b == 0) ? 0 : (ends[b - 1] + 1);
    int end = ends[b];
    float m = -INFINITY;
    for (int i = start + lane; i <= end; i += 64) m = fmaxf(m, logits[i]);
#pragma unroll
    for (int o = 32; o > 0; o >>= 1) m = fmaxf(m, __shfl_xor(m, o, 64));
    float ssum = 0.f;
    for (int i = start + lane; i <= end; i += 64) ssum += __expf(logits[i] - m);
#pragma unroll
    for (int o = 32; o > 0; o >>= 1) ssum += __shfl_xor(ssum, o, 64);
    float r = 1.f / ssum;
    for (int i = start + lane; i <= end; i += 64) out[i] = __expf(logits[i] - m) * r;
}

extern "C" void kernel_launch(void* const* d_in, const int* in_sizes, int n_in,
                              void* d_out, int out_size, void* d_ws, size_t ws_size,
                              hipStream_t stream) {
    const float* X  = (const float*)d_in[0];  // relation_embeds [N, D]
    const int*   q  = (const int*)d_in[1];    // queries [N]
    const float* Wq = (const float*)d_in[3];  // [A, D]
    const float* Wk = (const float*)d_in[4];  // [A, D]
    float* out = (float*)d_out;               // [N]

    char* ws = (char*)d_ws;
    size_t off = 0;
    auto alloc = [&](size_t bytes) -> char* {
        char* p = ws + off;
        off += (bytes + 255) & ~(size_t)255;
        return p;
    };
    int*   seg      = (int*)alloc((size_t)N * 4);
    int*   ends     = (int*)alloc((size_t)B * 4);
    int*   partials = (int*)alloc((size_t)NCHUNK * 4);
    int*   offs     = (int*)alloc((size_t)NCHUNK * 4);
    float* M        = (float*)alloc((size_t)D * D * 4);
    float* V        = (float*)alloc((size_t)B * D * 4);
    float* logits   = (float*)alloc((size_t)N * 4);

    k_scan_partials<<<NCHUNK, 256, 0, stream>>>(q, partials);
    k_scan_offsets<<<1, 256, 0, stream>>>(partials, offs);
    k_seg_ends<<<NCHUNK, 256, 0, stream>>>(q, offs, seg, ends);
    k_compute_M<<<D, 256, 0, stream>>>(Wq, Wk, M);
    k_compute_V<<<B, 256, 0, stream>>>(X, ends, M, V);
    k_logits<<<N / 4, 256, 0, stream>>>(X, seg, V, logits);
    k_softmax<<<B / 4, 256, 0, stream>>>(logits, ends, out);
}

// Round 2
// 413.845 us; speedup vs baseline: 1.1889x; 1.1889x over previous
//
#include <hip/hip_runtime.h>
#include <math.h>
#include <float.h>

// Problem constants (fixed by the reference):
constexpr int N = 262144;   // tokens
constexpr int B = 4096;     // segments
constexpr int D = 256;      // relation_embed_dim
constexpr int A = 128;      // attention_dim

constexpr int CHUNK  = 1024;       // queries elements per scan block
constexpr int NCHUNK = N / CHUNK;  // 256
constexpr int SEGB   = 8;          // segments per block in compute_V

// ---------- kernel 1: blocks [0,256) chunk sums of queries; blocks [256,512) M rows ----------
// M = Wk^T Wq  (D x D), M[d1][d2] = sum_a Wk[a][d1] * Wq[a][d2]
__global__ void k_partials_M(const int* __restrict__ q, int* __restrict__ partials,
                             const float* __restrict__ Wq, const float* __restrict__ Wk,
                             float* __restrict__ M) {
    int t = threadIdx.x;
    if (blockIdx.x < NCHUNK) {
        int4 v = ((const int4*)q)[blockIdx.x * (CHUNK / 4) + t];
        int s = v.x + v.y + v.z + v.w;
        __shared__ int sm[256];
        sm[t] = s; __syncthreads();
        for (int o = 128; o > 0; o >>= 1) {
            if (t < o) sm[t] += sm[t + o];
            __syncthreads();
        }
        if (t == 0) partials[blockIdx.x] = sm[0];
    } else {
        int d1 = blockIdx.x - NCHUNK;  // 0..255
        int d2 = t;                    // 0..255
        float acc = 0.f;
#pragma unroll 4
        for (int a = 0; a < A; a++) {
            acc = fmaf(Wk[a * D + d1], Wq[a * D + d2], acc);
        }
        M[d1 * D + d2] = acc;
    }
}

// ---------- kernel 2: per-token segment id + segment end indices ----------
// Each block re-scans the 256 partials locally (removes the 1-block serializing kernel).
__global__ void k_seg_ends(const int* __restrict__ q, const int* __restrict__ partials,
                           int* __restrict__ seg, int* __restrict__ ends) {
    int t = threadIdx.x;
    int bid = blockIdx.x;
    __shared__ int sp[256];   // scan of chunk partials
    __shared__ int sm[256];   // scan of per-thread sums within chunk
    sp[t] = partials[t];
    int4 v = ((const int4*)q)[bid * (CHUNK / 4) + t];
    int tsum = v.x + v.y + v.z + v.w;
    sm[t] = tsum;
    __syncthreads();
    for (int o = 1; o < 256; o <<= 1) {
        int a1 = (t >= o) ? sp[t - o] : 0;
        int a2 = (t >= o) ? sm[t - o] : 0;
        __syncthreads();
        sp[t] += a1;
        sm[t] += a2;
        __syncthreads();
    }
    int offs = (bid == 0) ? 0 : sp[bid - 1];          // ones in chunks before mine
    int run = offs + sm[t] - tsum;                    // ones strictly before my 4 elems
    int base_idx = bid * CHUNK + t * 4;
    int qq[4] = {v.x, v.y, v.z, v.w};
#pragma unroll
    for (int k = 0; k < 4; k++) {
        int idx = base_idx + k;
        seg[idx] = run;
        if (qq[k]) { ends[run] = idx; run++; }
    }
}

// ---------- kernel 3: V[b] = M * x_{end_b}  (B x D), 8 segments per block ----------
// x rows are block-uniform -> compiler can scalarize their loads (s_load), no LDS.
// Each thread walks its own M row linearly (L1-friendly), 8 accumulators.
__global__ void k_compute_V(const float* __restrict__ X, const int* __restrict__ ends,
                            const float* __restrict__ M, float* __restrict__ V) {
    int t = threadIdx.x;          // output dim d1
    int b0 = blockIdx.x * SEGB;
    const float4* xr[SEGB];
#pragma unroll
    for (int r = 0; r < SEGB; r++) {
        xr[r] = (const float4*)(X + (size_t)ends[b0 + r] * D);
    }
    const float4* Mrow = (const float4*)(M + t * D);
    float acc[SEGB];
#pragma unroll
    for (int r = 0; r < SEGB; r++) acc[r] = 0.f;
#pragma unroll 4
    for (int j = 0; j < D / 4; j++) {
        float4 m4 = Mrow[j];
#pragma unroll
        for (int r = 0; r < SEGB; r++) {
            float4 x4 = xr[r][j];
            acc[r] = fmaf(m4.x, x4.x, fmaf(m4.y, x4.y,
                     fmaf(m4.z, x4.z, fmaf(m4.w, x4.w, acc[r]))));
        }
    }
#pragma unroll
    for (int r = 0; r < SEGB; r++) V[(size_t)(b0 + r) * D + t] = acc[r];
}

// ---------- kernel 4: logits[i] = x_i . V[seg[i]] : one wave (64 lanes x float4) per token ----------
__global__ void k_logits(const float* __restrict__ X, const int* __restrict__ seg,
                         const float* __restrict__ V, float* __restrict__ logits) {
    int wave = threadIdx.x >> 6;  // 0..3
    int lane = threadIdx.x & 63;
    int tok = blockIdx.x * 4 + wave;
    float4 x4 = ((const float4*)(X + (size_t)tok * D))[lane];
    int s = seg[tok];
    float4 v4 = ((const float4*)(V + (size_t)s * D))[lane];
    float p = fmaf(x4.x, v4.x, fmaf(x4.y, v4.y, fmaf(x4.z, v4.z, x4.w * v4.w)));
#pragma unroll
    for (int o = 32; o > 0; o >>= 1) p += __shfl_xor(p, o, 64);
    if (lane == 0) logits[tok] = p;
}

// ---------- kernel 5: per-segment online softmax: one wave per segment, 2 passes ----------
__global__ void k_softmax(const float* __restrict__ logits, const int* __restrict__ ends,
                          float* __restrict__ out) {
    int wave = threadIdx.x >> 6;
    int lane = threadIdx.x & 63;
    int b = blockIdx.x * 4 + wave;
    int start = (b == 0) ? 0 : (ends[b - 1] + 1);
    int end = ends[b];
    // online (m, s) per lane; -FLT_MAX (not -inf) so empty-lane combines stay finite
    float m = -FLT_MAX, s = 0.f;
    for (int i = start + lane; i <= end; i += 64) {
        float x = logits[i];
        float nm = fmaxf(m, x);
        s = s * __expf(m - nm) + __expf(x - nm);
        m = nm;
    }
#pragma unroll
    for (int o = 32; o > 0; o >>= 1) {
        float mo = __shfl_xor(m, o, 64);
        float so = __shfl_xor(s, o, 64);
        float nm = fmaxf(m, mo);
        s = s * __expf(m - nm) + so * __expf(mo - nm);
        m = nm;
    }
    float r = 1.f / s;
    for (int i = start + lane; i <= end; i += 64) out[i] = __expf(logits[i] - m) * r;
}

extern "C" void kernel_launch(void* const* d_in, const int* in_sizes, int n_in,
                              void* d_out, int out_size, void* d_ws, size_t ws_size,
                              hipStream_t stream) {
    const float* X  = (const float*)d_in[0];  // relation_embeds [N, D]
    const int*   q  = (const int*)d_in[1];    // queries [N]
    const float* Wq = (const float*)d_in[3];  // [A, D]
    const float* Wk = (const float*)d_in[4];  // [A, D]
    float* out = (float*)d_out;               // [N]

    char* ws = (char*)d_ws;
    size_t off = 0;
    auto alloc = [&](size_t bytes) -> char* {
        char* p = ws + off;
        off += (bytes + 255) & ~(size_t)255;
        return p;
    };
    int*   seg      = (int*)alloc((size_t)N * 4);
    int*   ends     = (int*)alloc((size_t)B * 4);
    int*   partials = (int*)alloc((size_t)NCHUNK * 4);
    float* M        = (float*)alloc((size_t)D * D * 4);
    float* V        = (float*)alloc((size_t)B * D * 4);
    float* logits   = (float*)alloc((size_t)N * 4);

    k_partials_M<<<NCHUNK + D, 256, 0, stream>>>(q, partials, Wq, Wk, M);
    k_seg_ends<<<NCHUNK, 256, 0, stream>>>(q, partials, seg, ends);
    k_compute_V<<<B / SEGB, 256, 0, stream>>>(X, ends, M, V);
    k_logits<<<N / 4, 256, 0, stream>>>(X, seg, V, logits);
    k_softmax<<<B / 4, 256, 0, stream>>>(logits, ends, out);
}

// Round 4
// 406.460 us; speedup vs baseline: 1.2105x; 1.0182x over previous
//
#include <hip/hip_runtime.h>
#include <math.h>
#include <float.h>

// Problem constants (fixed by the reference):
constexpr int N = 262144;   // tokens
constexpr int B = 4096;     // segments
constexpr int D = 256;      // relation_embed_dim
constexpr int A = 128;      // attention_dim

constexpr int CHUNK  = 1024;       // queries elements per scan block
constexpr int NCHUNK = N / CHUNK;  // 256
constexpr int SEGB   = 8;          // segments per block in compute_V

// native clang vector type (works with __builtin_nontemporal_load)
typedef float fvec4 __attribute__((ext_vector_type(4)));

// ---------- kernel 1: blocks [0,256) chunk sums of queries; blocks [256,512) M rows ----------
// M = Wk^T Wq  (D x D), M[d1][d2] = sum_a Wk[a][d1] * Wq[a][d2]
__global__ void k_partials_M(const int* __restrict__ q, int* __restrict__ partials,
                             const float* __restrict__ Wq, const float* __restrict__ Wk,
                             float* __restrict__ M) {
    int t = threadIdx.x;
    if (blockIdx.x < NCHUNK) {
        int4 v = ((const int4*)q)[blockIdx.x * (CHUNK / 4) + t];
        int s = v.x + v.y + v.z + v.w;
        // wave reduce then 4-wave combine
        int lane = t & 63, w = t >> 6;
#pragma unroll
        for (int o = 32; o > 0; o >>= 1) s += __shfl_xor(s, o, 64);
        __shared__ int ws_[4];
        if (lane == 0) ws_[w] = s;
        __syncthreads();
        if (t == 0) partials[blockIdx.x] = ws_[0] + ws_[1] + ws_[2] + ws_[3];
    } else {
        int d1 = blockIdx.x - NCHUNK;  // 0..255
        int d2 = t;                    // 0..255
        float acc = 0.f;
#pragma unroll 4
        for (int a = 0; a < A; a++) {
            acc = fmaf(Wk[a * D + d1], Wq[a * D + d2], acc);
        }
        M[d1 * D + d2] = acc;
    }
}

// ---------- kernel 2: per-token segment id + segment end indices ----------
// Each block re-scans the 256 partials locally via wave-shuffle scans (1 barrier, not 16).
__global__ void k_seg_ends(const int* __restrict__ q, const int* __restrict__ partials,
                           int* __restrict__ seg, int* __restrict__ ends) {
    int t = threadIdx.x;
    int lane = t & 63, w = t >> 6;
    int bid = blockIdx.x;
    int p = partials[t];
    int4 v = ((const int4*)q)[bid * (CHUNK / 4) + t];
    int tsum = v.x + v.y + v.z + v.w;
    // inclusive shuffle scan of (p, tsum) within each wave
    int ps = p, ts = tsum;
#pragma unroll
    for (int o = 1; o < 64; o <<= 1) {
        int po = __shfl_up(ps, o, 64);
        int to = __shfl_up(ts, o, 64);
        if (lane >= o) { ps += po; ts += to; }
    }
    __shared__ int wp[4], wt[4];
    __shared__ int offs_sm;
    if (lane == 63) { wp[w] = ps; wt[w] = ts; }
    __syncthreads();
    int addp = 0, addt = 0;
#pragma unroll
    for (int i = 0; i < 4; i++) {
        if (i < w) { addp += wp[i]; addt += wt[i]; }
    }
    int sp_incl = ps + addp;   // inclusive scan of partials at index t
    int sm_incl = ts + addt;   // inclusive scan of per-thread chunk sums at t
    if (bid > 0 && t == bid - 1) offs_sm = sp_incl;  // partials sum over chunks < bid
    if (bid == 0 && t == 0) offs_sm = 0;
    __syncthreads();
    int run = offs_sm + sm_incl - tsum;  // ones strictly before my first elem
    int base_idx = bid * CHUNK + t * 4;
    int qq[4] = {v.x, v.y, v.z, v.w};
#pragma unroll
    for (int k = 0; k < 4; k++) {
        int idx = base_idx + k;
        seg[idx] = run;
        if (qq[k]) { ends[run] = idx; run++; }
    }
}

// ---------- kernel 3: V[b] = M * x_{end_b}  (B x D), 8 segments per block ----------
__global__ void k_compute_V(const float* __restrict__ X, const int* __restrict__ ends,
                            const float* __restrict__ M, float* __restrict__ V) {
    int t = threadIdx.x;          // output dim d1
    int b0 = blockIdx.x * SEGB;
    const float4* xr[SEGB];
#pragma unroll
    for (int r = 0; r < SEGB; r++) {
        xr[r] = (const float4*)(X + (size_t)ends[b0 + r] * D);
    }
    const float4* Mrow = (const float4*)(M + t * D);
    float acc[SEGB];
#pragma unroll
    for (int r = 0; r < SEGB; r++) acc[r] = 0.f;
#pragma unroll 4
    for (int j = 0; j < D / 4; j++) {
        float4 m4 = Mrow[j];
#pragma unroll
        for (int r = 0; r < SEGB; r++) {
            float4 x4 = xr[r][j];
            acc[r] = fmaf(m4.x, x4.x, fmaf(m4.y, x4.y,
                     fmaf(m4.z, x4.z, fmaf(m4.w, x4.w, acc[r]))));
        }
    }
#pragma unroll
    for (int r = 0; r < SEGB; r++) V[(size_t)(b0 + r) * D + t] = acc[r];
}

// ---------- kernel 4: logits[i] = x_i . V[seg[i]] : one wave per 2 tokens ----------
// X rows via nontemporal loads (pure streaming, keep V L2-resident); 4 outstanding
// 16B loads per lane; lane 0 stores both adjacent logits as one float2.
__global__ void k_logits(const float* __restrict__ X, const int* __restrict__ seg,
                         const float* __restrict__ V, float* __restrict__ logits) {
    int wave = threadIdx.x >> 6;  // 0..3
    int lane = threadIdx.x & 63;
    int tok0 = (blockIdx.x * 4 + wave) * 2;
    const fvec4* xa_p = (const fvec4*)(X + (size_t)tok0 * D) + lane;
    const fvec4* xb_p = (const fvec4*)(X + (size_t)(tok0 + 1) * D) + lane;
    fvec4 xa = __builtin_nontemporal_load(xa_p);
    fvec4 xb = __builtin_nontemporal_load(xb_p);
    int sa = seg[tok0];
    int sb = seg[tok0 + 1];
    float4 va = ((const float4*)(V + (size_t)sa * D))[lane];
    float4 vb = ((const float4*)(V + (size_t)sb * D))[lane];
    float pa = fmaf(xa.x, va.x, fmaf(xa.y, va.y, fmaf(xa.z, va.z, xa.w * va.w)));
    float pb = fmaf(xb.x, vb.x, fmaf(xb.y, vb.y, fmaf(xb.z, vb.z, xb.w * vb.w)));
#pragma unroll
    for (int o = 32; o > 0; o >>= 1) {
        pa += __shfl_xor(pa, o, 64);
        pb += __shfl_xor(pb, o, 64);
    }
    if (lane == 0) {
        float2 r = make_float2(pa, pb);
        *((float2*)(logits + tok0)) = r;
    }
}

// ---------- kernel 5: per-segment online softmax: one wave per segment, 2 passes ----------
__global__ void k_softmax(const float* __restrict__ logits, const int* __restrict__ ends,
                          float* __restrict__ out) {
    int wave = threadIdx.x >> 6;
    int lane = threadIdx.x & 63;
    int b = blockIdx.x * 4 + wave;
    int start = (b == 0) ? 0 : (ends[b - 1] + 1);
    int end = ends[b];
    // online (m, s) per lane; -FLT_MAX (not -inf) so empty-lane combines stay finite
    float m = -FLT_MAX, s = 0.f;
    for (int i = start + lane; i <= end; i += 64) {
        float x = logits[i];
        float nm = fmaxf(m, x);
        s = s * __expf(m - nm) + __expf(x - nm);
        m = nm;
    }
#pragma unroll
    for (int o = 32; o > 0; o >>= 1) {
        float mo = __shfl_xor(m, o, 64);
        float so = __shfl_xor(s, o, 64);
        float nm = fmaxf(m, mo);
        s = s * __expf(m - nm) + so * __expf(mo - nm);
        m = nm;
    }
    float r = 1.f / s;
    for (int i = start + lane; i <= end; i += 64) out[i] = __expf(logits[i] - m) * r;
}

extern "C" void kernel_launch(void* const* d_in, const int* in_sizes, int n_in,
                              void* d_out, int out_size, void* d_ws, size_t ws_size,
                              hipStream_t stream) {
    const float* X  = (const float*)d_in[0];  // relation_embeds [N, D]
    const int*   q  = (const int*)d_in[1];    // queries [N]
    const float* Wq = (const float*)d_in[3];  // [A, D]
    const float* Wk = (const float*)d_in[4];  // [A, D]
    float* out = (float*)d_out;               // [N]

    char* ws = (char*)d_ws;
    size_t off = 0;
    auto alloc = [&](size_t bytes) -> char* {
        char* p = ws + off;
        off += (bytes + 255) & ~(size_t)255;
        return p;
    };
    int*   seg      = (int*)alloc((size_t)N * 4);
    int*   ends     = (int*)alloc((size_t)B * 4);
    int*   partials = (int*)alloc((size_t)NCHUNK * 4);
    float* M        = (float*)alloc((size_t)D * D * 4);
    float* V        = (float*)alloc((size_t)B * D * 4);
    float* logits   = (float*)alloc((size_t)N * 4);

    k_partials_M<<<NCHUNK + D, 256, 0, stream>>>(q, partials, Wq, Wk, M);
    k_seg_ends<<<NCHUNK, 256, 0, stream>>>(q, partials, seg, ends);
    k_compute_V<<<B / SEGB, 256, 0, stream>>>(X, ends, M, V);
    k_logits<<<N / 8, 256, 0, stream>>>(X, seg, V, logits);
    k_softmax<<<B / 4, 256, 0, stream>>>(logits, ends, out);
}